// Round 12
// baseline (299.628 us; speedup 1.0000x reference)
//
#include <hip/hip_runtime.h>

#define HW (512 * 512)
#define QP 260   // pitch (floats): >=256, %8==4 -> phase-B row reads hit disjoint bank quads
#define WN 12288 // 192*64

typedef __bf16 bf16;
typedef __attribute__((ext_vector_type(8))) __bf16 bf16x8;
typedef __attribute__((ext_vector_type(4))) float f32x4;

__device__ __forceinline__ void cvt_split(float f, bf16& h, bf16& l) {
    h = (bf16)f;
    l = (bf16)(f - (float)h);
}

// Precompute: W -> bf16 hi/lo planes in d_ws (48 KB, L2-resident). (R8 form, verified)
__global__ __launch_bounds__(256) void wcvt_kernel(
    const float* __restrict__ w, bf16* __restrict__ wh, bf16* __restrict__ wl)
{
    const int i = blockIdx.x * 256 + threadIdx.x;
    if (i < WN) {
        bf16 h, l;
        cvt_split(w[i], h, l);
        wh[i] = h;
        wl[i] = l;
    }
}

// Single window per block, qk double-buffered by head parity -> ONE barrier per head.
// Schedule per head h (p=h&1):
//   A: read proj qk[p]+feat, elu, sums; write kf/av -> qk[p] rows 8-23 (own column)
//      shfl-reduce T-part -> tp[p][wvid];  wave fence (B reads only own wave's columns)
//   B: kv partials over own 64 px -> kvp[p][wvid*64+lane]
//   stage(h+1) -> qk[p^1]   (nobody reads qk[p^1] this interval)
//   S: __syncthreads  (the ONLY barrier)
//   D: wave-LOCAL kv reduce: kvsum = sum_g kvp[p][g*64+lane] -> kv_s[wvid*64+lane],
//      wave fence, uniform reads; T from tp[p]; ft; feat; out.
// Race audit: qk/kvp/tp parity-split across the barrier; kf/av column-exclusive;
// kv_s wave-private. No forced launch-bounds cap (R4/R5/R9: cap < natural => spill).
__global__ __launch_bounds__(256, 2) void lwmsa_kernel(
    const float* __restrict__ x,
    const bf16* __restrict__ wh,
    const bf16* __restrict__ wl,
    float* __restrict__ out)
{
    const int win  = blockIdx.x;       // 0..4095
    const int b    = win >> 10;
    const int wrow = (win >> 5) & 31;
    const int wcol = win & 31;
    const int n    = threadIdx.x;      // 0..255 = pixel in window
    const int lane = n & 63;
    const int wvid = n >> 6;           // wave 0..3
    const int c16  = lane & 15;
    const int q4   = lane >> 4;

    const int base = b * (64 * HW) + (wrow * 16 + (n >> 4)) * 512 + wcol * 16 + (n & 15);
    const int xwin = b * (64 * HW) + (wrow * 16) * 512 + wcol * 16;

    __shared__ float qk[2][24 * QP];   // parity: q rows 0-7, k 8-15, v 16-23
    __shared__ float kvp[2][256];      // parity: per-wave kv partials
    __shared__ float kv_s[256];        // wave-private kv broadcast segments
    __shared__ float tp[2][4];         // parity: k-sum partials per wave

    // ---- A-fragments (X), hi/lo, global -> registers, persistent across heads ----
    bf16x8 ah[2][4], al[2][4];
    #pragma unroll
    for (int ks = 0; ks < 2; ++ks)
        #pragma unroll
        for (int mt = 0; mt < 4; ++mt) {
            const int row = wvid * 4 + mt;
            const float* xp = x + xwin + row * 512 + c16 + (ks * 32 + q4 * 8) * HW;
            #pragma unroll
            for (int j = 0; j < 8; ++j) {
                bf16 h, l;
                cvt_split(xp[j * HW], h, l);
                ah[ks][mt][j] = h;
                al[ks][mt][j] = l;
            }
        }

    // ---- per-head MFMA + stage into qk[par] ----
    auto mfma_stage = [&](int hh, int par) {
        f32x4 acc[4][2];
        #pragma unroll
        for (int mt = 0; mt < 4; ++mt)
            #pragma unroll
            for (int nt = 0; nt < 2; ++nt)
                acc[mt][nt] = (f32x4){0.f, 0.f, 0.f, 0.f};

        #pragma unroll
        for (int ks = 0; ks < 2; ++ks) {
            #pragma unroll
            for (int nt = 0; nt < 2; ++nt) {
                const int ml   = nt * 16 + c16;                 // 0..31; valid < 24
                const int grow = (ml < 24) ? ((ml >> 3) * 64 + hh * 8 + (ml & 7))
                                           : (hh * 8);          // in-bounds dummy
                const int off  = grow * 64 + ks * 32 + q4 * 8;
                const bf16x8 bh = *(const bf16x8*)&wh[off];
                const bf16x8 bl = *(const bf16x8*)&wl[off];
                #pragma unroll
                for (int mt = 0; mt < 4; ++mt) {
                    acc[mt][nt] = __builtin_amdgcn_mfma_f32_16x16x32_bf16(ah[ks][mt], bh, acc[mt][nt], 0, 0, 0);
                    acc[mt][nt] = __builtin_amdgcn_mfma_f32_16x16x32_bf16(al[ks][mt], bh, acc[mt][nt], 0, 0, 0);
                    acc[mt][nt] = __builtin_amdgcn_mfma_f32_16x16x32_bf16(ah[ks][mt], bl, acc[mt][nt], 0, 0, 0);
                }
            }
        }

        // D: lane holds qkv-row ml=nt*16+c16 at px=(wvid*4+mt)*16+q4*4+reg
        #pragma unroll
        for (int nt = 0; nt < 2; ++nt) {
            const int ml = nt * 16 + c16;
            if (ml < 24) {
                #pragma unroll
                for (int mt = 0; mt < 4; ++mt) {
                    const int px = (wvid * 4 + mt) * 16 + q4 * 4;
                    *(float4*)&qk[par][ml * QP + px] = *(float4*)&acc[mt][nt];
                }
            }
        }
    };

    float feat[8];
    #pragma unroll
    for (int d = 0; d < 8; ++d) feat[d] = 0.f;

    mfma_stage(0, 0);
    __syncthreads();  // S_init: head-0 projections visible

    for (int h = 0; h < 8; ++h) {
        const int p = h & 1;

        // ---- phase A: proj+feat, elu1, row sums; write kf/av back (own column) ----
        float qf[8];
        float Sq = 0.f, tpart = 0.f;
        #pragma unroll
        for (int d = 0; d < 8; ++d) {
            const float aq = qk[p][d * QP + n]        + feat[d];
            const float ak = qk[p][(8 + d) * QP + n]  + feat[d];
            const float av = qk[p][(16 + d) * QP + n] + feat[d];
            qf[d] = aq > 0.f ? aq + 1.f : __expf(aq);
            const float kf = ak > 0.f ? ak + 1.f : __expf(ak);
            Sq    += qf[d];
            tpart += kf;
            qk[p][(8 + d) * QP + n]  = kf;
            qk[p][(16 + d) * QP + n] = av;
        }

        #pragma unroll
        for (int off = 1; off < 64; off <<= 1)
            tpart += __shfl_xor(tpart, off, 64);
        if (lane == 0) tp[p][wvid] = tpart;

        // wave-internal handoff: phase B reads only this wave's 64 columns (R8-verified)
        asm volatile("s_waitcnt lgkmcnt(0)" ::: "memory");

        // ---- phase B: kv partials over this wave's 64 px ----
        {
            const float4* kr = (const float4*)(qk[p] + (8 + (lane >> 3)) * QP + wvid * 64);
            const float4* vr = (const float4*)(qk[p] + (16 + (lane & 7)) * QP + wvid * 64);
            float s0 = 0.f, s1 = 0.f, s2 = 0.f, s3 = 0.f;
            #pragma unroll
            for (int j = 0; j < 16; ++j) {
                const float4 kk = kr[j];
                const float4 vv = vr[j];
                s0 = fmaf(kk.x, vv.x, s0);
                s1 = fmaf(kk.y, vv.y, s1);
                s2 = fmaf(kk.z, vv.z, s2);
                s3 = fmaf(kk.w, vv.w, s3);
            }
            kvp[p][wvid * 64 + lane] = (s0 + s1) + (s2 + s3);
        }

        // ---- stage next head into the OTHER parity buffer (nobody reads it now) ----
        if (h < 7)
            mfma_stage(h + 1, p ^ 1);

        __syncthreads();  // the single barrier: kvp[p], tp[p], qk[p^1] all visible

        // ---- phase D: wave-local kv reduce + rebroadcast, then z/feat/out ----
        {
            const float kvsum = (kvp[p][lane] + kvp[p][64 + lane]) +
                                (kvp[p][128 + lane] + kvp[p][192 + lane]);
            kv_s[wvid * 64 + lane] = kvsum;   // kv[lane>>3][lane&7] for this wave
        }
        asm volatile("s_waitcnt lgkmcnt(0)" ::: "memory");

        const float T  = ((tp[p][0] + tp[p][1]) + (tp[p][2] + tp[p][3])) + 8.0f * 1e-6f;
        const float zi = 1.0f / (Sq * T);

        float ft[8];
        #pragma unroll
        for (int d = 0; d < 8; ++d) ft[d] = 0.f;
        #pragma unroll
        for (int d = 0; d < 8; ++d) {
            const float qd = qf[d];
            const float4 a  = ((const float4*)(kv_s + wvid * 64 + d * 8))[0];
            const float4 bb = ((const float4*)(kv_s + wvid * 64 + d * 8))[1];
            ft[0] = fmaf(qd, a.x,  ft[0]);
            ft[1] = fmaf(qd, a.y,  ft[1]);
            ft[2] = fmaf(qd, a.z,  ft[2]);
            ft[3] = fmaf(qd, a.w,  ft[3]);
            ft[4] = fmaf(qd, bb.x, ft[4]);
            ft[5] = fmaf(qd, bb.y, ft[5]);
            ft[6] = fmaf(qd, bb.z, ft[6]);
            ft[7] = fmaf(qd, bb.w, ft[7]);
        }
        #pragma unroll
        for (int d = 0; d < 8; ++d) {
            feat[d] = ft[d] * zi;
            out[base + (h * 8 + d) * HW] = feat[d];
        }
    }
}

extern "C" void kernel_launch(void* const* d_in, const int* in_sizes, int n_in,
                              void* d_out, int out_size, void* d_ws, size_t ws_size,
                              hipStream_t stream) {
    const float* x  = (const float*)d_in[0];
    const float* w  = (const float*)d_in[1];
    float* out      = (float*)d_out;
    bf16* wh = (bf16*)d_ws;
    bf16* wl = wh + WN;
    wcvt_kernel<<<dim3((WN + 255) / 256), dim3(256), 0, stream>>>(w, wh, wl);
    lwmsa_kernel<<<dim3(4096), dim3(256), 0, stream>>>(x, wh, wl, out);
}

// Round 13
// 297.039 us; speedup vs baseline: 1.0087x; 1.0087x over previous
//
#include <hip/hip_runtime.h>

#define HW (512 * 512)
#define QP 260   // pitch (floats): >=256, %8==4 -> phase-B row reads hit disjoint bank quads
#define WN 12288 // 192*64

typedef __bf16 bf16;
typedef __attribute__((ext_vector_type(8))) __bf16 bf16x8;
typedef __attribute__((ext_vector_type(4))) float f32x4;

__device__ __forceinline__ void cvt_split(float f, bf16& h, bf16& l) {
    h = (bf16)f;
    l = (bf16)(f - (float)h);
}

// Precompute: W -> bf16 hi/lo planes in d_ws (48 KB, L2-resident). (verified R8+)
__global__ __launch_bounds__(256) void wcvt_kernel(
    const float* __restrict__ w, bf16* __restrict__ wh, bf16* __restrict__ wl)
{
    const int i = blockIdx.x * 256 + threadIdx.x;
    if (i < WN) {
        bf16 h, l;
        cvt_split(w[i], h, l);
        wh[i] = h;
        wl[i] = l;
    }
}

// R13: two windows per block (R10-verified), STAGGERED schedule.
// Per iteration h:
//   P1: D1(h-1) + A0(h) + B0(h)  (serial win0)  ||  stage(win1,h) + W(h) reg-loads
//   barrier
//   P2: D0(h)   + A1(h) + B1(h)  (serial win1)  ||  stage(win0,h+1) + W(h+1) reg-loads
//   barrier
// Every phase mixes serial VALU/LDS with 24 MFMAs + W vmem -> no exposed stage slot.
// Race audit: qk win-split (stage writes the idle window's buffer); kvp/tp win-split,
// writer->barrier->reader; kv_s reused per phase (barrier-separated, wave-private rows);
// kf/av writes column-exclusive; feat/qf register-carried.
// No launch-bounds cap below natural demand (R4/R5/R9: cap => spill traffic).
__global__ __launch_bounds__(256, 2) void lwmsa_kernel(
    const float* __restrict__ x,
    const bf16* __restrict__ wh,
    const bf16* __restrict__ wl,
    float* __restrict__ out)
{
    const int blk  = blockIdx.x;       // 0..2047
    const int b    = blk >> 9;
    const int wrow = (blk >> 4) & 31;
    const int wp   = blk & 15;         // col pair: wcol = 2*wp + w
    const int n    = threadIdx.x;      // 0..255 = pixel in window
    const int lane = n & 63;
    const int wvid = n >> 6;           // wave 0..3
    const int c16  = lane & 15;
    const int q4   = lane >> 4;

    __shared__ float qk[2][24 * QP];   // per window: q rows 0-7, k 8-15, v 16-23
    __shared__ float kvp[2][256];      // per window: per-wave kv partials
    __shared__ float kv_s[256];        // wave-private kv broadcast (reused per phase)
    __shared__ float tp[2][4];         // per window: k-sum partials per wave

    int base[2], xwin[2];
    #pragma unroll
    for (int w = 0; w < 2; ++w) {
        const int wcol = wp * 2 + w;
        base[w] = b * (64 * HW) + (wrow * 16 + (n >> 4)) * 512 + wcol * 16 + (n & 15);
        xwin[w] = b * (64 * HW) + (wrow * 16) * 512 + wcol * 16;
    }

    // ---- A-fragments (X) for both windows, hi/lo, global -> registers ----
    bf16x8 ah[2][2][4], al[2][2][4];   // [win][ks][mt]
    #pragma unroll
    for (int w = 0; w < 2; ++w)
        #pragma unroll
        for (int ks = 0; ks < 2; ++ks)
            #pragma unroll
            for (int mt = 0; mt < 4; ++mt) {
                const int row = wvid * 4 + mt;
                const float* xp = x + xwin[w] + row * 512 + c16 + (ks * 32 + q4 * 8) * HW;
                #pragma unroll
                for (int j = 0; j < 8; ++j) {
                    bf16 h, l;
                    cvt_split(xp[j * HW], h, l);
                    ah[w][ks][mt][j] = h;
                    al[w][ks][mt][j] = l;
                }
            }

    // ---- W fragments for one head, loaded to registers (issued at phase top) ----
    bf16x8 bhf[2][2], blf[2][2];       // [ks][nt]
    auto loadW = [&](int hh) {
        #pragma unroll
        for (int ks = 0; ks < 2; ++ks)
            #pragma unroll
            for (int nt = 0; nt < 2; ++nt) {
                const int ml   = nt * 16 + c16;                 // 0..31; valid < 24
                const int grow = (ml < 24) ? ((ml >> 3) * 64 + hh * 8 + (ml & 7))
                                           : (hh * 8);          // in-bounds dummy
                const int off  = grow * 64 + ks * 32 + q4 * 8;
                bhf[ks][nt] = *(const bf16x8*)&wh[off];
                blf[ks][nt] = *(const bf16x8*)&wl[off];
            }
    };

    // ---- MFMA + stage window w's 24 rows using the preloaded W fragments ----
    auto stage = [&](int w) {
        f32x4 acc[4][2];
        #pragma unroll
        for (int mt = 0; mt < 4; ++mt)
            #pragma unroll
            for (int nt = 0; nt < 2; ++nt)
                acc[mt][nt] = (f32x4){0.f, 0.f, 0.f, 0.f};

        #pragma unroll
        for (int ks = 0; ks < 2; ++ks)
            #pragma unroll
            for (int nt = 0; nt < 2; ++nt)
                #pragma unroll
                for (int mt = 0; mt < 4; ++mt) {
                    acc[mt][nt] = __builtin_amdgcn_mfma_f32_16x16x32_bf16(ah[w][ks][mt], bhf[ks][nt], acc[mt][nt], 0, 0, 0);
                    acc[mt][nt] = __builtin_amdgcn_mfma_f32_16x16x32_bf16(al[w][ks][mt], bhf[ks][nt], acc[mt][nt], 0, 0, 0);
                    acc[mt][nt] = __builtin_amdgcn_mfma_f32_16x16x32_bf16(ah[w][ks][mt], blf[ks][nt], acc[mt][nt], 0, 0, 0);
                }

        // D: lane holds qkv-row ml=nt*16+c16 at px=(wvid*4+mt)*16+q4*4+reg
        #pragma unroll
        for (int nt = 0; nt < 2; ++nt) {
            const int ml = nt * 16 + c16;
            if (ml < 24) {
                #pragma unroll
                for (int mt = 0; mt < 4; ++mt) {
                    const int px = (wvid * 4 + mt) * 16 + q4 * 4;
                    *(float4*)&qk[w][ml * QP + px] = *(float4*)&acc[mt][nt];
                }
            }
        }
    };

    float feat[2][8];
    #pragma unroll
    for (int w = 0; w < 2; ++w)
        #pragma unroll
        for (int d = 0; d < 8; ++d) feat[w][d] = 0.f;

    // ---- serial front half: proj+feat, elu1, sums, kf/av writeback, kv partials ----
    auto phaseAB = [&](int w, float (&qf)[8], float& Sq) {
        float tpart = 0.f;
        Sq = 0.f;
        #pragma unroll
        for (int d = 0; d < 8; ++d) {
            const float aq = qk[w][d * QP + n]        + feat[w][d];
            const float ak = qk[w][(8 + d) * QP + n]  + feat[w][d];
            const float av = qk[w][(16 + d) * QP + n] + feat[w][d];
            qf[d] = aq > 0.f ? aq + 1.f : __expf(aq);
            const float kf = ak > 0.f ? ak + 1.f : __expf(ak);
            Sq    += qf[d];
            tpart += kf;
            qk[w][(8 + d) * QP + n]  = kf;   // own column: no cross-thread hazard
            qk[w][(16 + d) * QP + n] = av;
        }

        #pragma unroll
        for (int off = 1; off < 64; off <<= 1)
            tpart += __shfl_xor(tpart, off, 64);
        if (lane == 0) tp[w][wvid] = tpart;

        // wave-internal handoff: B reads only this wave's 64 columns (R8-verified)
        asm volatile("s_waitcnt lgkmcnt(0)" ::: "memory");

        const float4* kr = (const float4*)(qk[w] + (8 + (lane >> 3)) * QP + wvid * 64);
        const float4* vr = (const float4*)(qk[w] + (16 + (lane & 7)) * QP + wvid * 64);
        float s0 = 0.f, s1 = 0.f, s2 = 0.f, s3 = 0.f;
        #pragma unroll
        for (int j = 0; j < 16; ++j) {
            const float4 kk = kr[j];
            const float4 vv = vr[j];
            s0 = fmaf(kk.x, vv.x, s0);
            s1 = fmaf(kk.y, vv.y, s1);
            s2 = fmaf(kk.z, vv.z, s2);
            s3 = fmaf(kk.w, vv.w, s3);
        }
        kvp[w][wvid * 64 + lane] = (s0 + s1) + (s2 + s3);
    };

    // ---- serial back half: kv reduce (wave-local), z, feat, out ----
    auto phaseD = [&](int w, const float (&qf)[8], float Sq, int h) {
        const float kvsum = (kvp[w][lane] + kvp[w][64 + lane]) +
                            (kvp[w][128 + lane] + kvp[w][192 + lane]);
        kv_s[wvid * 64 + lane] = kvsum;   // kv[lane>>3][lane&7], wave-private segment
        asm volatile("s_waitcnt lgkmcnt(0)" ::: "memory");

        const float T  = ((tp[w][0] + tp[w][1]) + (tp[w][2] + tp[w][3])) + 8.0f * 1e-6f;
        const float zi = 1.0f / (Sq * T);

        float ft[8];
        #pragma unroll
        for (int d = 0; d < 8; ++d) ft[d] = 0.f;
        #pragma unroll
        for (int d = 0; d < 8; ++d) {
            const float qd = qf[d];
            const float4 a  = ((const float4*)(kv_s + wvid * 64 + d * 8))[0];
            const float4 bb = ((const float4*)(kv_s + wvid * 64 + d * 8))[1];
            ft[0] = fmaf(qd, a.x,  ft[0]);
            ft[1] = fmaf(qd, a.y,  ft[1]);
            ft[2] = fmaf(qd, a.z,  ft[2]);
            ft[3] = fmaf(qd, a.w,  ft[3]);
            ft[4] = fmaf(qd, bb.x, ft[4]);
            ft[5] = fmaf(qd, bb.y, ft[5]);
            ft[6] = fmaf(qd, bb.z, ft[6]);
            ft[7] = fmaf(qd, bb.w, ft[7]);
        }
        #pragma unroll
        for (int d = 0; d < 8; ++d) {
            feat[w][d] = ft[d] * zi;
            out[base[w] + (h * 8 + d) * HW] = feat[w][d];
        }
    };

    float qf0[8], qf1[8];
    float Sq0 = 0.f, Sq1 = 0.f;

    // ---- prologue: stage win0 head 0 ----
    loadW(0);
    stage(0);
    __syncthreads();

    for (int h = 0; h < 8; ++h) {
        // P1: W(h) loads + D1(h-1) + A0/B0(h) + stage(win1,h)
        loadW(h);
        if (h > 0) phaseD(1, qf1, Sq1, h - 1);
        phaseAB(0, qf0, Sq0);
        stage(1);
        __syncthreads();

        // P2: W(h+1) loads + D0(h) + A1/B1(h) + stage(win0,h+1)
        if (h < 7) loadW(h + 1);
        phaseD(0, qf0, Sq0, h);
        phaseAB(1, qf1, Sq1);
        if (h < 7) stage(0);
        __syncthreads();
    }

    phaseD(1, qf1, Sq1, 7);
}

extern "C" void kernel_launch(void* const* d_in, const int* in_sizes, int n_in,
                              void* d_out, int out_size, void* d_ws, size_t ws_size,
                              hipStream_t stream) {
    const float* x  = (const float*)d_in[0];
    const float* w  = (const float*)d_in[1];
    float* out      = (float*)d_out;
    bf16* wh = (bf16*)d_ws;
    bf16* wl = wh + WN;
    wcvt_kernel<<<dim3((WN + 255) / 256), dim3(256), 0, stream>>>(w, wh, wl);
    lwmsa_kernel<<<dim3(2048), dim3(256), 0, stream>>>(x, wh, wl, out);
}